// Round 4
// baseline (162.789 us; speedup 1.0000x reference)
//
#include <hip/hip_runtime.h>

#define AS 20      // alphabet size
#define ASS 400    // AS*AS
#define KK 8
#define BB 256
#define MM 2
#define LL 1024

__device__ __forceinline__ float softplus_f(float x) {
    return x > 20.f ? x : log1pf(expf(x));
}

// wave-synchronous LDS fence: drain DS ops, forbid compiler reorder (rule #18)
__device__ __forceinline__ void wsync() {
    __builtin_amdgcn_sched_barrier(0);
    asm volatile("s_waitcnt lgkmcnt(0)" ::: "memory");
    __builtin_amdgcn_sched_barrier(0);
}

// wave-level 20x20 matmul C = A*B in wave-private LDS, lanes 0..49, 2x4 tiles
__device__ __forceinline__ void mul20w(const float* __restrict__ A,
                                       const float* __restrict__ B,
                                       float* __restrict__ C, int lane) {
    wsync();   // make prior writes to A/B visible
    if (lane < 50) {
        const int i2 = (lane / 5) * 2;
        const int c4 = (lane % 5) * 4;
        float a0[AS], a1[AS];
        #pragma unroll
        for (int q = 0; q < 5; q++) {
            float4 v0 = *(const float4*)&A[i2 * AS + 4 * q];
            float4 v1 = *(const float4*)&A[(i2 + 1) * AS + 4 * q];
            a0[4*q] = v0.x; a0[4*q+1] = v0.y; a0[4*q+2] = v0.z; a0[4*q+3] = v0.w;
            a1[4*q] = v1.x; a1[4*q+1] = v1.y; a1[4*q+2] = v1.z; a1[4*q+3] = v1.w;
        }
        float4 s0 = {0.f,0.f,0.f,0.f}, s1 = {0.f,0.f,0.f,0.f};
        #pragma unroll
        for (int z = 0; z < AS; z++) {
            float4 bv = *(const float4*)&B[z * AS + c4];
            s0.x = fmaf(a0[z], bv.x, s0.x); s0.y = fmaf(a0[z], bv.y, s0.y);
            s0.z = fmaf(a0[z], bv.z, s0.z); s0.w = fmaf(a0[z], bv.w, s0.w);
            s1.x = fmaf(a1[z], bv.x, s1.x); s1.y = fmaf(a1[z], bv.y, s1.y);
            s1.z = fmaf(a1[z], bv.z, s1.z); s1.w = fmaf(a1[z], bv.w, s1.w);
        }
        *(float4*)&C[i2 * AS + c4] = s0;
        *(float4*)&C[(i2 + 1) * AS + c4] = s1;
    }
}

// Full per-(m,b,k) P build executed by ONE wave in its private scratch W.
// W layout (floats): [0:400)=T [400:800)=T2 [800:1200)=T3 [1200:1600)=Xa
// [1600:2000)=Xb [2000:2020)=sp [2020:2040)=isp [2040:2060)=p [2060:2080)=rs
__device__ void expm_wave(const float* __restrict__ exch,
                          const float* __restrict__ eqk,
                          float tau_b, const float* __restrict__ pmr,
                          int mk, float* __restrict__ W,
                          float* __restrict__ Pk, int lane)
{
    float* T   = W;
    float* T2  = W + 400;
    float* T3  = W + 800;
    float* Xa  = W + 1200;
    float* Xb  = W + 1600;
    float* spv = W + 2000;
    float* ispv= W + 2020;
    float* pv  = W + 2040;
    float* rs  = W + 2060;

    const float* Km = exch + (size_t)mk * ASS;
    const float* ev = eqk + (size_t)mk * AS;

    // equilibrium distribution p, sqrt(p), 1/sqrt(p)
    if (lane < AS) {
        float mx = -1e30f;
        for (int i = 0; i < AS; i++) mx = fmaxf(mx, ev[i]);
        float sum = 0.f;
        for (int i = 0; i < AS; i++) sum += expf(ev[i] - mx);
        float pl = expf(ev[lane] - mx) / sum;
        pv[lane] = pl;
        float sq = sqrtf(pl);
        spv[lane] = sq;
        ispv[lane] = 1.0f / sq;
    }
    wsync();
    // Xa = R * p_j  (R = softplus(sym(K)), zero diag)
    for (int f = lane; f < ASS; f += 64) {
        int i = f / AS, j = f % AS;
        float Kv = 0.5f * (Km[i*AS+j] + Km[j*AS+i]);
        float Rv = (i == j) ? 0.f : softplus_f(Kv);
        Xa[f] = Rv * pv[j];
    }
    wsync();
    if (lane < AS) {
        float r = 0.f;
        for (int j = 0; j < AS; j++) r += Xa[lane*AS+j];
        rs[lane] = r;
    }
    wsync();
    float mue = 0.f;
    for (int i = 0; i < AS; i++) mue += pv[i] * rs[i];
    const float inv_mue = 1.0f / fmaxf(mue, 1e-16f);
    const float tau = tau_b * softplus_f(pmr[mk]);
    // Xb = sp_i * Q_ij * isp_j
    for (int f = lane; f < ASS; f += 64) {
        int i = f/AS, j = f%AS;
        float Qv = (Xa[f] - (i==j ? rs[i] : 0.f)) * inv_mue;
        Xb[f] = spv[i] * Qv * ispv[j];
    }
    wsync();
    // Xa = symmetrized Ssym
    for (int f = lane; f < ASS; f += 64) {
        int i = f/AS, j = f%AS;
        Xa[f] = 0.5f * (Xb[f] + Xb[j*AS+i]);
    }
    wsync();
    if (lane < AS) {
        float r = 0.f;
        for (int j = 0; j < AS; j++) r += fabsf(Xa[lane*AS+j]);
        rs[lane] = r;
    }
    wsync();
    float nrm = 0.f;
    for (int i = 0; i < AS; i++) nrm = fmaxf(nrm, rs[i]);
    const float nt = tau * nrm;
    int s = 0;
    if (nt > 1.0f) {
        s = (int)ceilf(log2f(nt));
        if (s < 0) s = 0;
        if (s > 30) s = 30;
    }
    const float sc = ldexpf(tau, -s);
    for (int f = lane; f < ASS; f += 64) T[f] = sc * Xa[f];

    mul20w(T,  T, T2, lane);
    mul20w(T2, T, T3, lane);

    const float C2 = 0.5f, C3 = 1.f/6.f, C4 = 1.f/24.f, C5 = 1.f/120.f,
                C6 = 1.f/720.f, C7 = 1.f/5040.f, C8 = 1.f/40320.f, C9 = 1.f/362880.f;
    wsync();
    for (int f = lane; f < ASS; f += 64) {
        int i = f/AS, j = f%AS;
        Xa[f] = ((i == j) ? C6 : 0.f) + C7*T[f] + C8*T2[f] + C9*T3[f];
    }
    mul20w(T3, Xa, Xb, lane);
    wsync();
    for (int f = lane; f < ASS; f += 64) {
        int i = f/AS, j = f%AS;
        Xa[f] = ((i == j) ? C3 : 0.f) + C4*T[f] + C5*T2[f] + Xb[f];
    }
    mul20w(T3, Xa, Xb, lane);
    wsync();
    for (int f = lane; f < ASS; f += 64) {
        int i = f/AS, j = f%AS;
        Xa[f] = ((i == j) ? 1.f : 0.f) + T[f] + C2*T2[f] + Xb[f];
    }
    for (int q = 0; q < s; q++) {     // s is wave-uniform
        if ((q & 1) == 0) mul20w(Xa, Xa, Xb, lane);
        else              mul20w(Xb, Xb, Xa, lane);
    }
    wsync();
    const float* E = (s & 1) ? Xb : Xa;
    for (int f = lane; f < ASS; f += 64) {
        int i = f/AS, j = f%AS;
        Pk[f] = ispv[i] * E[f] * spv[j];
    }
    // block-level visibility provided by caller's __syncthreads
}

// Fused: per (m,b) block — phase 1: 8 expm's across 5 waves (wave-sync);
// phase 2: out[l, k*20+s] = sum_z seq[l,z] * P[k][z,s], dbuf over 16 chunks.
__global__ __launch_bounds__(320, 2) void fused_anc(
    const float* __restrict__ seq, const float* __restrict__ exch,
    const float* __restrict__ eqk, const float* __restrict__ tauk,
    const float* __restrict__ pmr, float* __restrict__ out)
{
    // pool: 5 waves x 2080 scratch floats = [0,10400) ; P = [10400,13600)
    __shared__ __align__(16) float pool[13600];   // 54.4 KB
    const int mb = blockIdx.x;           // m*BB + b
    const int mi = mb / BB;
    const int t  = threadIdx.x;
    const int w  = t >> 6;
    const int lane = t & 63;

    const float* seqb = seq + (size_t)mb * LL * AS;
    float* outb = out + (size_t)mb * LL * (KK * AS);

    // prefetch apply chunk 0 while expm runs
    const float4 first = ((const float4*)seqb)[t];

    const float tau_b = softplus_f(tauk[mb]);
    float* W  = pool + w * 2080;
    float* Pl = pool + 10400;

    // wave w: k = w, then k = w+5 (waves 0..2 only)
    expm_wave(exch, eqk, tau_b, pmr, mi*KK + w, W, Pl + w*ASS, lane);
    if (w < 3) {
        const int k2 = w + 5;
        expm_wave(exch, eqk, tau_b, pmr, mi*KK + k2, W, Pl + k2*ASS, lane);
    }
    __syncthreads();

    // ---- apply phase ----
    const int j  = t % 40;        // cols 4j..4j+3
    const int rg = t / 40;        // row group 0..7
    const int ki = j / 5;
    const int s0 = (j % 5) * 4;

    float4 Preg[AS];
    {
        const float* Pm = Pl + ki * ASS + s0;
        #pragma unroll
        for (int z = 0; z < AS; z++) Preg[z] = *(const float4*)(Pm + z * AS);
    }
    float4* sbuf = (float4*)pool;   // 2 x 320 float4 = 10240 B, reuses scratch
    sbuf[t] = first;
    __syncthreads();

    for (int c = 0; c < 16; c++) {
        const int cur = c & 1;
        float4 rnext;
        if (c < 15)   // early-issue next chunk's global load
            rnext = ((const float4*)(seqb + (size_t)(c + 1) * 64 * AS))[t];
        const int l0 = c * 64;
        #pragma unroll
        for (int rr = 0; rr < 8; rr++) {
            const int lr = rg * 8 + rr;
            const float4* row = &sbuf[cur * 320 + lr * 5];
            float4 acc = {0.f, 0.f, 0.f, 0.f};
            #pragma unroll
            for (int q = 0; q < 5; q++) {
                float4 sv = row[q];
                acc.x = fmaf(sv.x, Preg[4*q+0].x, acc.x); acc.y = fmaf(sv.x, Preg[4*q+0].y, acc.y);
                acc.z = fmaf(sv.x, Preg[4*q+0].z, acc.z); acc.w = fmaf(sv.x, Preg[4*q+0].w, acc.w);
                acc.x = fmaf(sv.y, Preg[4*q+1].x, acc.x); acc.y = fmaf(sv.y, Preg[4*q+1].y, acc.y);
                acc.z = fmaf(sv.y, Preg[4*q+1].z, acc.z); acc.w = fmaf(sv.y, Preg[4*q+1].w, acc.w);
                acc.x = fmaf(sv.z, Preg[4*q+2].x, acc.x); acc.y = fmaf(sv.z, Preg[4*q+2].y, acc.y);
                acc.z = fmaf(sv.z, Preg[4*q+2].z, acc.z); acc.w = fmaf(sv.z, Preg[4*q+2].w, acc.w);
                acc.x = fmaf(sv.w, Preg[4*q+3].x, acc.x); acc.y = fmaf(sv.w, Preg[4*q+3].y, acc.y);
                acc.z = fmaf(sv.w, Preg[4*q+3].z, acc.z); acc.w = fmaf(sv.w, Preg[4*q+3].w, acc.w);
            }
            *(float4*)&outb[(size_t)(l0 + lr) * 160 + 4 * j] = acc;
        }
        if (c < 15) sbuf[(cur ^ 1) * 320 + t] = rnext;
        __syncthreads();
    }
}

extern "C" void kernel_launch(void* const* d_in, const int* in_sizes, int n_in,
                              void* d_out, int out_size, void* d_ws, size_t ws_size,
                              hipStream_t stream) {
    const float* seq  = (const float*)d_in[0];
    const float* exch = (const float*)d_in[1];
    const float* eqk  = (const float*)d_in[2];
    const float* tauk = (const float*)d_in[3];
    const float* pmr  = (const float*)d_in[4];
    float* out = (float*)d_out;

    fused_anc<<<dim3(MM * BB), dim3(320), 0, stream>>>(seq, exch, eqk, tauk, pmr, out);
}